// Round 7
// baseline (83.305 us; speedup 1.0000x reference)
//
#include <hip/hip_runtime.h>
#include <hip/hip_bf16.h>
#include <stdint.h>

#define NB 2
#define SEQ 4096
#define HID 256
#define NHEAD 8
#define NKVH 4
#define HDIM 32

typedef __bf16 bf16;
typedef __bf16 bf16x8 __attribute__((ext_vector_type(8)));
typedef float f32x4 __attribute__((ext_vector_type(4)));

static __device__ __forceinline__ uint16_t bfbits(float f) {
    bf16 h = (bf16)f;
    return __builtin_bit_cast(uint16_t, h);
}
static __device__ __forceinline__ uint32_t pack_bf16(float lo, float hi) {
    return (uint32_t)bfbits(lo) | ((uint32_t)bfbits(hi) << 16);
}
// raw v_exp_f32: no libm range wrapper.  exp2(-1e30) == +0 in HW.
static __device__ __forceinline__ float fexp2(float x) {
#if __has_builtin(__builtin_amdgcn_exp2f)
    return __builtin_amdgcn_exp2f(x);
#else
    float r; asm("v_exp_f32 %0, %1" : "=v"(r) : "v"(x)); return r;
#endif
}

// ---------------------------------------------------------------------------
// Kernel 1: QKV projection + RoPE (unchanged).
// ---------------------------------------------------------------------------
__global__ __launch_bounds__(256) void qkv_proj(
    const float* __restrict__ hs, const float* __restrict__ Wq,
    const float* __restrict__ Wk, const float* __restrict__ Wv,
    bf16* __restrict__ qws, bf16* __restrict__ kws, bf16* __restrict__ vtws)
{
    __shared__ bf16 As[64][136];
    __shared__ bf16 Bs[64][136];
    const int t = threadIdx.x;
    const int wid = t >> 6, lane = t & 63;
    const int g = lane >> 4, c = lane & 15;
    const int n0 = blockIdx.x * 64;
    const int m0 = blockIdx.y * 64;

    const float* bsrc; int ro;
    if (n0 < 256)      { bsrc = Wq; ro = n0; }
    else if (n0 < 384) { bsrc = Wk; ro = n0 - 256; }
    else               { bsrc = Wv; ro = n0 - 384; }

    const f32x4 zf = {0.f, 0.f, 0.f, 0.f};
    f32x4 acc[4] = {zf, zf, zf, zf};

    const int c4 = t & 31;
    const int rb = t >> 5;

    for (int ks = 0; ks < 256; ks += 128) {
        __syncthreads();
        #pragma unroll
        for (int i = 0; i < 8; ++i) {
            int row = i * 8 + rb;
            float4 v = *(const float4*)&hs[(size_t)(m0 + row) * HID + ks + c4 * 4];
            ushort4 w; w.x = bfbits(v.x); w.y = bfbits(v.y); w.z = bfbits(v.z); w.w = bfbits(v.w);
            *(ushort4*)&As[row][c4 * 4] = w;
        }
        #pragma unroll
        for (int i = 0; i < 8; ++i) {
            int row = i * 8 + rb;
            float4 v = *(const float4*)&bsrc[(size_t)(ro + row) * HID + ks + c4 * 4];
            ushort4 w; w.x = bfbits(v.x); w.y = bfbits(v.y); w.z = bfbits(v.z); w.w = bfbits(v.w);
            *(ushort4*)&Bs[row][c4 * 4] = w;
        }
        __syncthreads();
        #pragma unroll
        for (int kk = 0; kk < 128; kk += 32) {
            bf16x8 af = *(const bf16x8*)&As[wid * 16 + c][kk + g * 8];
            #pragma unroll
            for (int nt = 0; nt < 4; ++nt) {
                bf16x8 bfr = *(const bf16x8*)&Bs[nt * 16 + c][kk + g * 8];
                acc[nt] = __builtin_amdgcn_mfma_f32_16x16x32_bf16(af, bfr, acc[nt], 0, 0, 0);
            }
        }
    }

    const float qscale = 1.4426950408889634f * 0.17677669529663687f; // log2e/sqrt(32)
    const float invf = exp2f(-0.83048202372184f * (float)c);          // 10000^(-c/16)
    #pragma unroll
    for (int r = 0; r < 4; ++r) {
        int m = m0 + wid * 16 + g * 4 + r;
        int b = m >> 12, s = m & (SEQ - 1);
        float sn, cs;
        sincosf((float)s * invf, &sn, &cs);
        if (n0 < 256) {
            #pragma unroll
            for (int np = 0; np < 4; np += 2) {
                int h = (n0 + np * 16) >> 5;
                float x1 = acc[np][r], x2 = acc[np + 1][r];
                float y1 = (x1 * cs - x2 * sn) * qscale;
                float y2 = (x2 * cs + x1 * sn) * qscale;
                size_t base = ((size_t)(b * NHEAD + h) * SEQ + s) * HDIM;
                qws[base + c] = (bf16)y1;
                qws[base + 16 + c] = (bf16)y2;
            }
        } else if (n0 < 384) {
            #pragma unroll
            for (int np = 0; np < 4; np += 2) {
                int kh = (n0 - 256 + np * 16) >> 5;
                float x1 = acc[np][r], x2 = acc[np + 1][r];
                float y1 = x1 * cs - x2 * sn;
                float y2 = x2 * cs + x1 * sn;
                size_t base = ((size_t)(b * NKVH + kh) * SEQ + s) * HDIM;
                kws[base + c] = (bf16)y1;
                kws[base + 16 + c] = (bf16)y2;
            }
        } else {
            #pragma unroll
            for (int nt = 0; nt < 4; ++nt) {
                int ng = n0 + nt * 16 + c - 384;
                int vh = ng >> 5, d = ng & 31;
                vtws[((size_t)(b * NKVH + vh) * HDIM + d) * SEQ + s] = (bf16)acc[nt][r];
            }
        }
    }
}

// ---------------------------------------------------------------------------
// Kernel 2: causal flash attention, LDS-staged double-buffered, 32 q / wave.
// Block = 4 waves x 32 queries = 128-query tile; one tile per block.
// Each K/V fragment read from LDS feeds TWO 16-q subtiles (halves LDS
// traffic per unit work vs R6).  Descending-T dispatch: longest blocks
// first, 512 blocks over 256 CUs dynamically balance the causal skew.
// Shuffle-free S->P->PV via permuted K rows; no-max softmax; l via
// ones-MFMA.  h = wgid&7 pins each KV stream to one XCD's L2.
// ---------------------------------------------------------------------------
__global__ __launch_bounds__(256, 2) void attn_fwd(
    const bf16* __restrict__ qws, const bf16* __restrict__ kws,
    const bf16* __restrict__ vtws, bf16* __restrict__ att)
{
    __shared__ bf16 Kb[2][64 * 32];     // [key][d] linear
    __shared__ bf16 Vb[2][32 * 64];     // [d][key], byte ^= ((d&7)<<4)
    __shared__ float tr[4][16 * 33];
    const int t = threadIdx.x;
    const int w = t >> 6, lane = t & 63;
    const int g = lane >> 4, c = lane & 15;
    const int wg = blockIdx.x;
    const int h = wg & 7;                    // XCD pin
    const int rest = wg >> 3;
    const int b = rest & 1;
    const int T = 31 - (rest >> 1);          // descending workload: longest first
    const int kvh = h >> 1;
    const bf16* Kg = kws + (size_t)(b * NKVH + kvh) * SEQ * HDIM;
    const bf16* Vg = vtws + (size_t)(b * NKVH + kvh) * HDIM * SEQ;
    const int nsteps = 2 * T + 2;            // 64-key chunks to cover [0, (T+1)*128)
    const int q0 = T * 128 + w * 32;         // wave's first query
    const int d_w = 2 * T + (w >> 1);        // wave's diagonal chunk (both subtiles)

    const bf16* Qb = qws + (size_t)(b * NHEAD + h) * SEQ * HDIM;
    bf16x8 qf0 = *(const bf16x8*)&Qb[(size_t)(q0 + c) * HDIM + g * 8];
    bf16x8 qf1 = *(const bf16x8*)&Qb[(size_t)(q0 + 16 + c) * HDIM + g * 8];

    // staging mapping: thread -> 16B of K and 16B of V^T per chunk
    const int sd = t >> 3, sseg = t & 7;
    char* kdst[2] = { (char*)&Kb[0][0] + t * 16, (char*)&Kb[1][0] + t * 16 };
    const int vdo = sd * 128 + ((sseg * 16) ^ ((sd & 7) << 4));
    char* vdst[2] = { (char*)&Vb[0][0] + vdo, (char*)&Vb[1][0] + vdo };
    const bf16* kg_t = Kg + t * 8;                         // + ch*2048 elems
    const bf16* vg_t = Vg + (size_t)sd * SEQ + sseg * 8;   // + ch*64 elems

    // fragment read offsets
    const int kperm = 8 * (c >> 2) + (c & 3);
    const int kro = kperm * 64 + g * 16;           // byte offset in Kb
    const int cx = c & 7;
    const int vro0 = c * 128, vro1 = (16 + c) * 128;

    const f32x4 zf = {0.f, 0.f, 0.f, 0.f};
    union { uint32_t u[4]; bf16x8 v; } onesf;
    onesf.u[0] = onesf.u[1] = onesf.u[2] = onesf.u[3] = 0x3F803F80u;

    f32x4 o00 = zf, o01 = zf, ol0 = zf;      // subtile 0 (q0..q0+15)
    f32x4 o10 = zf, o11 = zf, ol1 = zf;      // subtile 1 (q0+16..q0+31)

    // prologue: stage chunk 0
    {
        uint4 ka = *(const uint4*)kg_t;
        uint4 va = *(const uint4*)vg_t;
        *(uint4*)kdst[0] = ka;
        *(uint4*)vdst[0] = va;
    }
    __syncthreads();

    #pragma unroll 1
    for (int s = 0; s < nsteps; ++s) {
        // (1) issue global loads for chunk s+1
        uint4 ka, va;
        const int sn = s + 1;
        if (sn < nsteps) {
            ka = *(const uint4*)(kg_t + sn * 2048);
            va = *(const uint4*)(vg_t + sn * 64);
        }
        // (2) compute chunk s from buf[s&1] (skip if past this wave's diagonal)
        if (s <= d_w) {
            const char* kbuf = (const char*)&Kb[s & 1][0];
            const char* vbuf = (const char*)&Vb[s & 1][0];

            bf16x8 kf0 = *(const bf16x8*)(kbuf + kro);
            bf16x8 kf1 = *(const bf16x8*)(kbuf + kro + 256);
            bf16x8 kf2 = *(const bf16x8*)(kbuf + kro + 2048);
            bf16x8 kf3 = *(const bf16x8*)(kbuf + kro + 2304);
            bf16x8 vf00 = *(const bf16x8*)(vbuf + vro0 + ((g ^ cx) << 4));
            bf16x8 vf01 = *(const bf16x8*)(vbuf + vro1 + ((g ^ cx) << 4));
            bf16x8 vf10 = *(const bf16x8*)(vbuf + vro0 + (((4 + g) ^ cx) << 4));
            bf16x8 vf11 = *(const bf16x8*)(vbuf + vro1 + (((4 + g) ^ cx) << 4));

            const bool diag = (s == d_w);
            const int qbase = (w & 1) * 32 + c;

            // ---- subtile 0 ----
            {
                f32x4 st0 = __builtin_amdgcn_mfma_f32_16x16x32_bf16(kf0, qf0, zf, 0, 0, 0);
                f32x4 st1 = __builtin_amdgcn_mfma_f32_16x16x32_bf16(kf1, qf0, zf, 0, 0, 0);
                f32x4 st2 = __builtin_amdgcn_mfma_f32_16x16x32_bf16(kf2, qf0, zf, 0, 0, 0);
                f32x4 st3 = __builtin_amdgcn_mfma_f32_16x16x32_bf16(kf3, qf0, zf, 0, 0, 0);
                if (diag) {
                    const int qoff = qbase;
                    #pragma unroll
                    for (int r = 0; r < 4; ++r) {
                        if (8 * g + r > qoff)          st0[r] = -1e30f;
                        if (8 * g + 4 + r > qoff)      st1[r] = -1e30f;
                        if (32 + 8 * g + r > qoff)     st2[r] = -1e30f;
                        if (32 + 8 * g + 4 + r > qoff) st3[r] = -1e30f;
                    }
                }
                float p00 = fexp2(st0[0]), p01 = fexp2(st0[1]), p02 = fexp2(st0[2]), p03 = fexp2(st0[3]);
                float p10 = fexp2(st1[0]), p11 = fexp2(st1[1]), p12 = fexp2(st1[2]), p13 = fexp2(st1[3]);
                float p20 = fexp2(st2[0]), p21 = fexp2(st2[1]), p22 = fexp2(st2[2]), p23 = fexp2(st2[3]);
                float p30 = fexp2(st3[0]), p31 = fexp2(st3[1]), p32 = fexp2(st3[2]), p33 = fexp2(st3[3]);
                union { uint32_t u[4]; bf16x8 v; } pb0, pb1;
                asm("v_cvt_pk_bf16_f32 %0, %1, %2" : "=v"(pb0.u[0]) : "v"(p00), "v"(p01));
                asm("v_cvt_pk_bf16_f32 %0, %1, %2" : "=v"(pb0.u[1]) : "v"(p02), "v"(p03));
                asm("v_cvt_pk_bf16_f32 %0, %1, %2" : "=v"(pb0.u[2]) : "v"(p10), "v"(p11));
                asm("v_cvt_pk_bf16_f32 %0, %1, %2" : "=v"(pb0.u[3]) : "v"(p12), "v"(p13));
                asm("v_cvt_pk_bf16_f32 %0, %1, %2" : "=v"(pb1.u[0]) : "v"(p20), "v"(p21));
                asm("v_cvt_pk_bf16_f32 %0, %1, %2" : "=v"(pb1.u[1]) : "v"(p22), "v"(p23));
                asm("v_cvt_pk_bf16_f32 %0, %1, %2" : "=v"(pb1.u[2]) : "v"(p30), "v"(p31));
                asm("v_cvt_pk_bf16_f32 %0, %1, %2" : "=v"(pb1.u[3]) : "v"(p32), "v"(p33));
                o00 = __builtin_amdgcn_mfma_f32_16x16x32_bf16(vf00, pb0.v, o00, 0, 0, 0);
                o01 = __builtin_amdgcn_mfma_f32_16x16x32_bf16(vf01, pb0.v, o01, 0, 0, 0);
                ol0 = __builtin_amdgcn_mfma_f32_16x16x32_bf16(onesf.v, pb0.v, ol0, 0, 0, 0);
                o00 = __builtin_amdgcn_mfma_f32_16x16x32_bf16(vf10, pb1.v, o00, 0, 0, 0);
                o01 = __builtin_amdgcn_mfma_f32_16x16x32_bf16(vf11, pb1.v, o01, 0, 0, 0);
                ol0 = __builtin_amdgcn_mfma_f32_16x16x32_bf16(onesf.v, pb1.v, ol0, 0, 0, 0);
            }
            // ---- subtile 1 ----
            {
                f32x4 st0 = __builtin_amdgcn_mfma_f32_16x16x32_bf16(kf0, qf1, zf, 0, 0, 0);
                f32x4 st1 = __builtin_amdgcn_mfma_f32_16x16x32_bf16(kf1, qf1, zf, 0, 0, 0);
                f32x4 st2 = __builtin_amdgcn_mfma_f32_16x16x32_bf16(kf2, qf1, zf, 0, 0, 0);
                f32x4 st3 = __builtin_amdgcn_mfma_f32_16x16x32_bf16(kf3, qf1, zf, 0, 0, 0);
                if (diag) {
                    const int qoff = qbase + 16;
                    #pragma unroll
                    for (int r = 0; r < 4; ++r) {
                        if (8 * g + r > qoff)          st0[r] = -1e30f;
                        if (8 * g + 4 + r > qoff)      st1[r] = -1e30f;
                        if (32 + 8 * g + r > qoff)     st2[r] = -1e30f;
                        if (32 + 8 * g + 4 + r > qoff) st3[r] = -1e30f;
                    }
                }
                float p00 = fexp2(st0[0]), p01 = fexp2(st0[1]), p02 = fexp2(st0[2]), p03 = fexp2(st0[3]);
                float p10 = fexp2(st1[0]), p11 = fexp2(st1[1]), p12 = fexp2(st1[2]), p13 = fexp2(st1[3]);
                float p20 = fexp2(st2[0]), p21 = fexp2(st2[1]), p22 = fexp2(st2[2]), p23 = fexp2(st2[3]);
                float p30 = fexp2(st3[0]), p31 = fexp2(st3[1]), p32 = fexp2(st3[2]), p33 = fexp2(st3[3]);
                union { uint32_t u[4]; bf16x8 v; } pb0, pb1;
                asm("v_cvt_pk_bf16_f32 %0, %1, %2" : "=v"(pb0.u[0]) : "v"(p00), "v"(p01));
                asm("v_cvt_pk_bf16_f32 %0, %1, %2" : "=v"(pb0.u[1]) : "v"(p02), "v"(p03));
                asm("v_cvt_pk_bf16_f32 %0, %1, %2" : "=v"(pb0.u[2]) : "v"(p10), "v"(p11));
                asm("v_cvt_pk_bf16_f32 %0, %1, %2" : "=v"(pb0.u[3]) : "v"(p12), "v"(p13));
                asm("v_cvt_pk_bf16_f32 %0, %1, %2" : "=v"(pb1.u[0]) : "v"(p20), "v"(p21));
                asm("v_cvt_pk_bf16_f32 %0, %1, %2" : "=v"(pb1.u[1]) : "v"(p22), "v"(p23));
                asm("v_cvt_pk_bf16_f32 %0, %1, %2" : "=v"(pb1.u[2]) : "v"(p30), "v"(p31));
                asm("v_cvt_pk_bf16_f32 %0, %1, %2" : "=v"(pb1.u[3]) : "v"(p32), "v"(p33));
                o10 = __builtin_amdgcn_mfma_f32_16x16x32_bf16(vf00, pb0.v, o10, 0, 0, 0);
                o11 = __builtin_amdgcn_mfma_f32_16x16x32_bf16(vf01, pb0.v, o11, 0, 0, 0);
                ol1 = __builtin_amdgcn_mfma_f32_16x16x32_bf16(onesf.v, pb0.v, ol1, 0, 0, 0);
                o10 = __builtin_amdgcn_mfma_f32_16x16x32_bf16(vf10, pb1.v, o10, 0, 0, 0);
                o11 = __builtin_amdgcn_mfma_f32_16x16x32_bf16(vf11, pb1.v, o11, 0, 0, 0);
                ol1 = __builtin_amdgcn_mfma_f32_16x16x32_bf16(onesf.v, pb1.v, ol1, 0, 0, 0);
            }
        }
        // (3) write staged chunk s+1 into buf[(s+1)&1]
        if (sn < nsteps) {
            *(uint4*)kdst[sn & 1] = ka;
            *(uint4*)vdst[sn & 1] = va;
        }
        __syncthreads();
    }

    // epilogue: both subtiles (per-wave private tr slice, sequential -> safe)
    #pragma unroll 1
    for (int j = 0; j < 2; ++j) {
        f32x4 a0 = j ? o10 : o00;
        f32x4 a1 = j ? o11 : o01;
        f32x4 al = j ? ol1 : ol0;
        float inv = 1.0f / al[0];
        #pragma unroll
        for (int r = 0; r < 4; ++r) {
            tr[w][c * 33 + 4 * g + r]      = a0[r] * inv;
            tr[w][c * 33 + 16 + 4 * g + r] = a1[r] * inv;
        }
        int q = lane >> 2, dp = (lane & 3) * 8;
        uint32_t u0 = pack_bf16(tr[w][q * 33 + dp + 0], tr[w][q * 33 + dp + 1]);
        uint32_t u1 = pack_bf16(tr[w][q * 33 + dp + 2], tr[w][q * 33 + dp + 3]);
        uint32_t u2 = pack_bf16(tr[w][q * 33 + dp + 4], tr[w][q * 33 + dp + 5]);
        uint32_t u3 = pack_bf16(tr[w][q * 33 + dp + 6], tr[w][q * 33 + dp + 7]);
        size_t base = ((size_t)b * SEQ + q0 + j * 16 + q) * HID + h * HDIM + dp;
        *(uint4*)&att[base] = make_uint4(u0, u1, u2, u3);
    }
}

// ---------------------------------------------------------------------------
// Kernel 3: output projection (unchanged).
// ---------------------------------------------------------------------------
__global__ __launch_bounds__(256) void out_proj(
    const bf16* __restrict__ att, const float* __restrict__ Wo,
    float* __restrict__ out)
{
    __shared__ bf16 As[64][136];
    __shared__ bf16 Bs[64][136];
    const int t = threadIdx.x;
    const int wid = t >> 6, lane = t & 63;
    const int g = lane >> 4, c = lane & 15;
    const int n0 = blockIdx.x * 64;
    const int m0 = blockIdx.y * 64;

    const f32x4 zf = {0.f, 0.f, 0.f, 0.f};
    f32x4 acc[4] = {zf, zf, zf, zf};

    const int c4 = t & 31;
    const int rb = t >> 5;

    for (int ks = 0; ks < 256; ks += 128) {
        __syncthreads();
        #pragma unroll
        for (int i = 0; i < 8; ++i) {
            int row = i * 8 + rb;
            ushort4 v = *(const ushort4*)&att[(size_t)(m0 + row) * HID + ks + c4 * 4];
            *(ushort4*)&As[row][c4 * 4] = v;
        }
        #pragma unroll
        for (int i = 0; i < 8; ++i) {
            int row = i * 8 + rb;
            float4 v = *(const float4*)&Wo[(size_t)(n0 + row) * HID + ks + c4 * 4];
            ushort4 w; w.x = bfbits(v.x); w.y = bfbits(v.y); w.z = bfbits(v.z); w.w = bfbits(v.w);
            *(ushort4*)&Bs[row][c4 * 4] = w;
        }
        __syncthreads();
        #pragma unroll
        for (int kk = 0; kk < 128; kk += 32) {
            bf16x8 af = *(const bf16x8*)&As[wid * 16 + c][kk + g * 8];
            #pragma unroll
            for (int nt = 0; nt < 4; ++nt) {
                bf16x8 bfr = *(const bf16x8*)&Bs[nt * 16 + c][kk + g * 8];
                acc[nt] = __builtin_amdgcn_mfma_f32_16x16x32_bf16(af, bfr, acc[nt], 0, 0, 0);
            }
        }
    }

    #pragma unroll
    for (int nt = 0; nt < 4; ++nt) {
        #pragma unroll
        for (int r = 0; r < 4; ++r) {
            int m = m0 + wid * 16 + g * 4 + r;
            out[(size_t)m * HID + n0 + nt * 16 + c] = acc[nt][r];
        }
    }
}

extern "C" void kernel_launch(void* const* d_in, const int* in_sizes, int n_in,
                              void* d_out, int out_size, void* d_ws, size_t ws_size,
                              hipStream_t stream) {
    const float* hs = (const float*)d_in[0];
    const float* Wq = (const float*)d_in[1];
    const float* Wk = (const float*)d_in[2];
    const float* Wv = (const float*)d_in[3];
    const float* Wo = (const float*)d_in[4];
    char* ws = (char*)d_ws;
    bf16* qws  = (bf16*)(ws);                 // [2][8][4096][32]  4,194,304 B
    bf16* kws  = (bf16*)(ws + 4194304);       // [2][4][4096][32]  2,097,152 B
    bf16* vtws = (bf16*)(ws + 6291456);       // [2][4][32][4096]  2,097,152 B
    bf16* att  = (bf16*)(ws + 8388608);       // [2][4096][256]    4,194,304 B

    qkv_proj<<<dim3(8, 128), 256, 0, stream>>>(hs, Wq, Wk, Wv, qws, kws, vtws);
    attn_fwd<<<512, 256, 0, stream>>>(qws, kws, vtws, att);
    out_proj<<<dim3(4, 128), 256, 0, stream>>>(att, Wo, (float*)d_out);
}

// Round 8
// 68.099 us; speedup vs baseline: 1.2233x; 1.2233x over previous
//
#include <hip/hip_runtime.h>
#include <hip/hip_bf16.h>
#include <stdint.h>

#define NB 2
#define SEQ 4096
#define HID 256
#define NHEAD 8
#define NKVH 4
#define HDIM 32

typedef __bf16 bf16;
typedef __bf16 bf16x8 __attribute__((ext_vector_type(8)));
typedef float f32x4 __attribute__((ext_vector_type(4)));

static __device__ __forceinline__ uint16_t bfbits(float f) {
    bf16 h = (bf16)f;
    return __builtin_bit_cast(uint16_t, h);
}
static __device__ __forceinline__ uint32_t pack_bf16(float lo, float hi) {
    return (uint32_t)bfbits(lo) | ((uint32_t)bfbits(hi) << 16);
}
// raw v_exp_f32: no libm range wrapper.  exp2(-1e30) == +0 in HW.
static __device__ __forceinline__ float fexp2(float x) {
#if __has_builtin(__builtin_amdgcn_exp2f)
    return __builtin_amdgcn_exp2f(x);
#else
    float r; asm("v_exp_f32 %0, %1" : "=v"(r) : "v"(x)); return r;
#endif
}
// async global->LDS DMA, 16B per lane.  LDS dest = wave-uniform base +
// lane*16 (hardware rule); global src is per-lane.
static __device__ __forceinline__ void gld_lds16(const void* g, void* l) {
    __builtin_amdgcn_global_load_lds(
        (const __attribute__((address_space(1))) void*)g,
        (__attribute__((address_space(3))) void*)l, 16, 0, 0);
}

// ---------------------------------------------------------------------------
// Kernel 1: QKV projection + RoPE (unchanged).
// ---------------------------------------------------------------------------
__global__ __launch_bounds__(256) void qkv_proj(
    const float* __restrict__ hs, const float* __restrict__ Wq,
    const float* __restrict__ Wk, const float* __restrict__ Wv,
    bf16* __restrict__ qws, bf16* __restrict__ kws, bf16* __restrict__ vtws)
{
    __shared__ bf16 As[64][136];
    __shared__ bf16 Bs[64][136];
    const int t = threadIdx.x;
    const int wid = t >> 6, lane = t & 63;
    const int g = lane >> 4, c = lane & 15;
    const int n0 = blockIdx.x * 64;
    const int m0 = blockIdx.y * 64;

    const float* bsrc; int ro;
    if (n0 < 256)      { bsrc = Wq; ro = n0; }
    else if (n0 < 384) { bsrc = Wk; ro = n0 - 256; }
    else               { bsrc = Wv; ro = n0 - 384; }

    const f32x4 zf = {0.f, 0.f, 0.f, 0.f};
    f32x4 acc[4] = {zf, zf, zf, zf};

    const int c4 = t & 31;
    const int rb = t >> 5;

    for (int ks = 0; ks < 256; ks += 128) {
        __syncthreads();
        #pragma unroll
        for (int i = 0; i < 8; ++i) {
            int row = i * 8 + rb;
            float4 v = *(const float4*)&hs[(size_t)(m0 + row) * HID + ks + c4 * 4];
            ushort4 w; w.x = bfbits(v.x); w.y = bfbits(v.y); w.z = bfbits(v.z); w.w = bfbits(v.w);
            *(ushort4*)&As[row][c4 * 4] = w;
        }
        #pragma unroll
        for (int i = 0; i < 8; ++i) {
            int row = i * 8 + rb;
            float4 v = *(const float4*)&bsrc[(size_t)(ro + row) * HID + ks + c4 * 4];
            ushort4 w; w.x = bfbits(v.x); w.y = bfbits(v.y); w.z = bfbits(v.z); w.w = bfbits(v.w);
            *(ushort4*)&Bs[row][c4 * 4] = w;
        }
        __syncthreads();
        #pragma unroll
        for (int kk = 0; kk < 128; kk += 32) {
            bf16x8 af = *(const bf16x8*)&As[wid * 16 + c][kk + g * 8];
            #pragma unroll
            for (int nt = 0; nt < 4; ++nt) {
                bf16x8 bfr = *(const bf16x8*)&Bs[nt * 16 + c][kk + g * 8];
                acc[nt] = __builtin_amdgcn_mfma_f32_16x16x32_bf16(af, bfr, acc[nt], 0, 0, 0);
            }
        }
    }

    const float qscale = 1.4426950408889634f * 0.17677669529663687f; // log2e/sqrt(32)
    const float invf = exp2f(-0.83048202372184f * (float)c);          // 10000^(-c/16)
    #pragma unroll
    for (int r = 0; r < 4; ++r) {
        int m = m0 + wid * 16 + g * 4 + r;
        int b = m >> 12, s = m & (SEQ - 1);
        float sn, cs;
        sincosf((float)s * invf, &sn, &cs);
        if (n0 < 256) {
            #pragma unroll
            for (int np = 0; np < 4; np += 2) {
                int h = (n0 + np * 16) >> 5;
                float x1 = acc[np][r], x2 = acc[np + 1][r];
                float y1 = (x1 * cs - x2 * sn) * qscale;
                float y2 = (x2 * cs + x1 * sn) * qscale;
                size_t base = ((size_t)(b * NHEAD + h) * SEQ + s) * HDIM;
                qws[base + c] = (bf16)y1;
                qws[base + 16 + c] = (bf16)y2;
            }
        } else if (n0 < 384) {
            #pragma unroll
            for (int np = 0; np < 4; np += 2) {
                int kh = (n0 - 256 + np * 16) >> 5;
                float x1 = acc[np][r], x2 = acc[np + 1][r];
                float y1 = x1 * cs - x2 * sn;
                float y2 = x2 * cs + x1 * sn;
                size_t base = ((size_t)(b * NKVH + kh) * SEQ + s) * HDIM;
                kws[base + c] = (bf16)y1;
                kws[base + 16 + c] = (bf16)y2;
            }
        } else {
            #pragma unroll
            for (int nt = 0; nt < 4; ++nt) {
                int ng = n0 + nt * 16 + c - 384;
                int vh = ng >> 5, d = ng & 31;
                vtws[((size_t)(b * NKVH + vh) * HDIM + d) * SEQ + s] = (bf16)acc[nt][r];
            }
        }
    }
}

// ---------------------------------------------------------------------------
// Kernel 2: causal flash attention, 32 q/wave, ASYNC global_load_lds staging.
// The chunk-(s+1) K/V loads are issued as global_load_lds DMA at the TOP of
// step s -- no VGPR round trip, nothing for the compiler to sink; the
// __syncthreads() at step end emits the vmcnt(0) drain.  LDS dest is linear
// (wave-uniform base + lane*16, HW rule); the V bank-swizzle is applied to
// the GLOBAL source address (sseg ^ (sd&7), involution), read side unchanged.
// Shuffle-free S->P->PV via permuted K rows; no-max softmax; l via ones-MFMA.
// Descending-T dispatch balances causal skew; h = wgid&7 pins KV to one XCD.
// ---------------------------------------------------------------------------
__global__ __launch_bounds__(256, 2) void attn_fwd(
    const bf16* __restrict__ qws, const bf16* __restrict__ kws,
    const bf16* __restrict__ vtws, bf16* __restrict__ att)
{
    __shared__ bf16 Kb[2][64 * 32];     // [key][d] linear
    __shared__ bf16 Vb[2][32 * 64];     // [d][key], swizzled via global src
    __shared__ float tr[4][16 * 33];
    const int t = threadIdx.x;
    const int w = t >> 6, lane = t & 63;
    const int g = lane >> 4, c = lane & 15;
    const int wg = blockIdx.x;
    const int h = wg & 7;                    // XCD pin
    const int rest = wg >> 3;
    const int b = rest & 1;
    const int T = 31 - (rest >> 1);          // descending workload: longest first
    const int kvh = h >> 1;
    const bf16* Kg = kws + (size_t)(b * NKVH + kvh) * SEQ * HDIM;
    const bf16* Vg = vtws + (size_t)(b * NKVH + kvh) * HDIM * SEQ;
    const int nsteps = 2 * T + 2;            // 64-key chunks covering [0,(T+1)*128)
    const int q0 = T * 128 + w * 32;         // wave's first query
    const int d_w = 2 * T + (w >> 1);        // wave's diagonal chunk

    const bf16* Qb = qws + (size_t)(b * NHEAD + h) * SEQ * HDIM;
    bf16x8 qf0 = *(const bf16x8*)&Qb[(size_t)(q0 + c) * HDIM + g * 8];
    bf16x8 qf1 = *(const bf16x8*)&Qb[(size_t)(q0 + 16 + c) * HDIM + g * 8];

    // async staging: per-lane global src, wave-uniform LDS dest (+lane*16 HW)
    const int sd = t >> 3, sseg = t & 7;
    const bf16* kg_t = Kg + t * 8;                                  // + ch*2048
    const bf16* vg_t = Vg + (size_t)sd * SEQ + (sseg ^ (sd & 7)) * 8; // + ch*64
    char* kl[2] = { (char*)&Kb[0][0] + w * 1024, (char*)&Kb[1][0] + w * 1024 };
    char* vl[2] = { (char*)&Vb[0][0] + w * 1024, (char*)&Vb[1][0] + w * 1024 };

    // fragment read offsets
    const int kperm = 8 * (c >> 2) + (c & 3);
    const int kro = kperm * 64 + g * 16;           // byte offset in Kb
    const int cx = c & 7;
    const int vro0 = c * 128, vro1 = (16 + c) * 128;

    const f32x4 zf = {0.f, 0.f, 0.f, 0.f};
    union { uint32_t u[4]; bf16x8 v; } onesf;
    onesf.u[0] = onesf.u[1] = onesf.u[2] = onesf.u[3] = 0x3F803F80u;

    f32x4 o00 = zf, o01 = zf, ol0 = zf;      // subtile 0 (q0..q0+15)
    f32x4 o10 = zf, o11 = zf, ol1 = zf;      // subtile 1 (q0+16..q0+31)

    // prologue: stage chunk 0
    gld_lds16(kg_t, kl[0]);
    gld_lds16(vg_t, vl[0]);
    __syncthreads();

    #pragma unroll 1
    for (int s = 0; s < nsteps; ++s) {
        // (1) issue async DMA for chunk s+1 into the other buffer
        const int sn = s + 1;
        if (sn < nsteps) {
            gld_lds16(kg_t + sn * 2048, kl[sn & 1]);
            gld_lds16(vg_t + sn * 64, vl[sn & 1]);
        }
        // (2) compute chunk s from buf[s&1] (skip if past this wave's diagonal)
        if (s <= d_w) {
            const char* kbuf = (const char*)&Kb[s & 1][0];
            const char* vbuf = (const char*)&Vb[s & 1][0];

            bf16x8 kf0 = *(const bf16x8*)(kbuf + kro);
            bf16x8 kf1 = *(const bf16x8*)(kbuf + kro + 256);
            bf16x8 kf2 = *(const bf16x8*)(kbuf + kro + 2048);
            bf16x8 kf3 = *(const bf16x8*)(kbuf + kro + 2304);
            bf16x8 vf00 = *(const bf16x8*)(vbuf + vro0 + ((g ^ cx) << 4));
            bf16x8 vf01 = *(const bf16x8*)(vbuf + vro1 + ((g ^ cx) << 4));
            bf16x8 vf10 = *(const bf16x8*)(vbuf + vro0 + (((4 + g) ^ cx) << 4));
            bf16x8 vf11 = *(const bf16x8*)(vbuf + vro1 + (((4 + g) ^ cx) << 4));

            const bool diag = (s == d_w);
            const int qbase = (w & 1) * 32 + c;

            // ---- subtile 0 ----
            {
                f32x4 st0 = __builtin_amdgcn_mfma_f32_16x16x32_bf16(kf0, qf0, zf, 0, 0, 0);
                f32x4 st1 = __builtin_amdgcn_mfma_f32_16x16x32_bf16(kf1, qf0, zf, 0, 0, 0);
                f32x4 st2 = __builtin_amdgcn_mfma_f32_16x16x32_bf16(kf2, qf0, zf, 0, 0, 0);
                f32x4 st3 = __builtin_amdgcn_mfma_f32_16x16x32_bf16(kf3, qf0, zf, 0, 0, 0);
                if (diag) {
                    const int qoff = qbase;
                    #pragma unroll
                    for (int r = 0; r < 4; ++r) {
                        if (8 * g + r > qoff)          st0[r] = -1e30f;
                        if (8 * g + 4 + r > qoff)      st1[r] = -1e30f;
                        if (32 + 8 * g + r > qoff)     st2[r] = -1e30f;
                        if (32 + 8 * g + 4 + r > qoff) st3[r] = -1e30f;
                    }
                }
                float p00 = fexp2(st0[0]), p01 = fexp2(st0[1]), p02 = fexp2(st0[2]), p03 = fexp2(st0[3]);
                float p10 = fexp2(st1[0]), p11 = fexp2(st1[1]), p12 = fexp2(st1[2]), p13 = fexp2(st1[3]);
                float p20 = fexp2(st2[0]), p21 = fexp2(st2[1]), p22 = fexp2(st2[2]), p23 = fexp2(st2[3]);
                float p30 = fexp2(st3[0]), p31 = fexp2(st3[1]), p32 = fexp2(st3[2]), p33 = fexp2(st3[3]);
                union { uint32_t u[4]; bf16x8 v; } pb0, pb1;
                asm("v_cvt_pk_bf16_f32 %0, %1, %2" : "=v"(pb0.u[0]) : "v"(p00), "v"(p01));
                asm("v_cvt_pk_bf16_f32 %0, %1, %2" : "=v"(pb0.u[1]) : "v"(p02), "v"(p03));
                asm("v_cvt_pk_bf16_f32 %0, %1, %2" : "=v"(pb0.u[2]) : "v"(p10), "v"(p11));
                asm("v_cvt_pk_bf16_f32 %0, %1, %2" : "=v"(pb0.u[3]) : "v"(p12), "v"(p13));
                asm("v_cvt_pk_bf16_f32 %0, %1, %2" : "=v"(pb1.u[0]) : "v"(p20), "v"(p21));
                asm("v_cvt_pk_bf16_f32 %0, %1, %2" : "=v"(pb1.u[1]) : "v"(p22), "v"(p23));
                asm("v_cvt_pk_bf16_f32 %0, %1, %2" : "=v"(pb1.u[2]) : "v"(p30), "v"(p31));
                asm("v_cvt_pk_bf16_f32 %0, %1, %2" : "=v"(pb1.u[3]) : "v"(p32), "v"(p33));
                o00 = __builtin_amdgcn_mfma_f32_16x16x32_bf16(vf00, pb0.v, o00, 0, 0, 0);
                o01 = __builtin_amdgcn_mfma_f32_16x16x32_bf16(vf01, pb0.v, o01, 0, 0, 0);
                ol0 = __builtin_amdgcn_mfma_f32_16x16x32_bf16(onesf.v, pb0.v, ol0, 0, 0, 0);
                o00 = __builtin_amdgcn_mfma_f32_16x16x32_bf16(vf10, pb1.v, o00, 0, 0, 0);
                o01 = __builtin_amdgcn_mfma_f32_16x16x32_bf16(vf11, pb1.v, o01, 0, 0, 0);
                ol0 = __builtin_amdgcn_mfma_f32_16x16x32_bf16(onesf.v, pb1.v, ol0, 0, 0, 0);
            }
            // ---- subtile 1 ----
            {
                f32x4 st0 = __builtin_amdgcn_mfma_f32_16x16x32_bf16(kf0, qf1, zf, 0, 0, 0);
                f32x4 st1 = __builtin_amdgcn_mfma_f32_16x16x32_bf16(kf1, qf1, zf, 0, 0, 0);
                f32x4 st2 = __builtin_amdgcn_mfma_f32_16x16x32_bf16(kf2, qf1, zf, 0, 0, 0);
                f32x4 st3 = __builtin_amdgcn_mfma_f32_16x16x32_bf16(kf3, qf1, zf, 0, 0, 0);
                if (diag) {
                    const int qoff = qbase + 16;
                    #pragma unroll
                    for (int r = 0; r < 4; ++r) {
                        if (8 * g + r > qoff)          st0[r] = -1e30f;
                        if (8 * g + 4 + r > qoff)      st1[r] = -1e30f;
                        if (32 + 8 * g + r > qoff)     st2[r] = -1e30f;
                        if (32 + 8 * g + 4 + r > qoff) st3[r] = -1e30f;
                    }
                }
                float p00 = fexp2(st0[0]), p01 = fexp2(st0[1]), p02 = fexp2(st0[2]), p03 = fexp2(st0[3]);
                float p10 = fexp2(st1[0]), p11 = fexp2(st1[1]), p12 = fexp2(st1[2]), p13 = fexp2(st1[3]);
                float p20 = fexp2(st2[0]), p21 = fexp2(st2[1]), p22 = fexp2(st2[2]), p23 = fexp2(st2[3]);
                float p30 = fexp2(st3[0]), p31 = fexp2(st3[1]), p32 = fexp2(st3[2]), p33 = fexp2(st3[3]);
                union { uint32_t u[4]; bf16x8 v; } pb0, pb1;
                asm("v_cvt_pk_bf16_f32 %0, %1, %2" : "=v"(pb0.u[0]) : "v"(p00), "v"(p01));
                asm("v_cvt_pk_bf16_f32 %0, %1, %2" : "=v"(pb0.u[1]) : "v"(p02), "v"(p03));
                asm("v_cvt_pk_bf16_f32 %0, %1, %2" : "=v"(pb0.u[2]) : "v"(p10), "v"(p11));
                asm("v_cvt_pk_bf16_f32 %0, %1, %2" : "=v"(pb0.u[3]) : "v"(p12), "v"(p13));
                asm("v_cvt_pk_bf16_f32 %0, %1, %2" : "=v"(pb1.u[0]) : "v"(p20), "v"(p21));
                asm("v_cvt_pk_bf16_f32 %0, %1, %2" : "=v"(pb1.u[1]) : "v"(p22), "v"(p23));
                asm("v_cvt_pk_bf16_f32 %0, %1, %2" : "=v"(pb1.u[2]) : "v"(p30), "v"(p31));
                asm("v_cvt_pk_bf16_f32 %0, %1, %2" : "=v"(pb1.u[3]) : "v"(p32), "v"(p33));
                o10 = __builtin_amdgcn_mfma_f32_16x16x32_bf16(vf00, pb0.v, o10, 0, 0, 0);
                o11 = __builtin_amdgcn_mfma_f32_16x16x32_bf16(vf01, pb0.v, o11, 0, 0, 0);
                ol1 = __builtin_amdgcn_mfma_f32_16x16x32_bf16(onesf.v, pb0.v, ol1, 0, 0, 0);
                o10 = __builtin_amdgcn_mfma_f32_16x16x32_bf16(vf10, pb1.v, o10, 0, 0, 0);
                o11 = __builtin_amdgcn_mfma_f32_16x16x32_bf16(vf11, pb1.v, o11, 0, 0, 0);
                ol1 = __builtin_amdgcn_mfma_f32_16x16x32_bf16(onesf.v, pb1.v, ol1, 0, 0, 0);
            }
        }
        // (3) barrier: drains the DMA (vmcnt 0) + orders LDS reuse
        __syncthreads();
    }

    // epilogue: both subtiles (per-wave private tr slice, sequential -> safe)
    #pragma unroll 1
    for (int j = 0; j < 2; ++j) {
        f32x4 a0 = j ? o10 : o00;
        f32x4 a1 = j ? o11 : o01;
        f32x4 al = j ? ol1 : ol0;
        float inv = 1.0f / al[0];
        #pragma unroll
        for (int r = 0; r < 4; ++r) {
            tr[w][c * 33 + 4 * g + r]      = a0[r] * inv;
            tr[w][c * 33 + 16 + 4 * g + r] = a1[r] * inv;
        }
        int q = lane >> 2, dp = (lane & 3) * 8;
        uint32_t u0 = pack_bf16(tr[w][q * 33 + dp + 0], tr[w][q * 33 + dp + 1]);
        uint32_t u1 = pack_bf16(tr[w][q * 33 + dp + 2], tr[w][q * 33 + dp + 3]);
        uint32_t u2 = pack_bf16(tr[w][q * 33 + dp + 4], tr[w][q * 33 + dp + 5]);
        uint32_t u3 = pack_bf16(tr[w][q * 33 + dp + 6], tr[w][q * 33 + dp + 7]);
        size_t base = ((size_t)b * SEQ + q0 + j * 16 + q) * HID + h * HDIM + dp;
        *(uint4*)&att[base] = make_uint4(u0, u1, u2, u3);
    }
}

// ---------------------------------------------------------------------------
// Kernel 3: output projection (unchanged).
// ---------------------------------------------------------------------------
__global__ __launch_bounds__(256) void out_proj(
    const bf16* __restrict__ att, const float* __restrict__ Wo,
    float* __restrict__ out)
{
    __shared__ bf16 As[64][136];
    __shared__ bf16 Bs[64][136];
    const int t = threadIdx.x;
    const int wid = t >> 6, lane = t & 63;
    const int g = lane >> 4, c = lane & 15;
    const int n0 = blockIdx.x * 64;
    const int m0 = blockIdx.y * 64;

    const f32x4 zf = {0.f, 0.f, 0.f, 0.f};
    f32x4 acc[4] = {zf, zf, zf, zf};

    const int c4 = t & 31;
    const int rb = t >> 5;

    for (int ks = 0; ks < 256; ks += 128) {
        __syncthreads();
        #pragma unroll
        for (int i = 0; i < 8; ++i) {
            int row = i * 8 + rb;
            ushort4 v = *(const ushort4*)&att[(size_t)(m0 + row) * HID + ks + c4 * 4];
            *(ushort4*)&As[row][c4 * 4] = v;
        }
        #pragma unroll
        for (int i = 0; i < 8; ++i) {
            int row = i * 8 + rb;
            float4 v = *(const float4*)&Wo[(size_t)(n0 + row) * HID + ks + c4 * 4];
            ushort4 w; w.x = bfbits(v.x); w.y = bfbits(v.y); w.z = bfbits(v.z); w.w = bfbits(v.w);
            *(ushort4*)&Bs[row][c4 * 4] = w;
        }
        __syncthreads();
        #pragma unroll
        for (int kk = 0; kk < 128; kk += 32) {
            bf16x8 af = *(const bf16x8*)&As[wid * 16 + c][kk + g * 8];
            #pragma unroll
            for (int nt = 0; nt < 4; ++nt) {
                bf16x8 bfr = *(const bf16x8*)&Bs[nt * 16 + c][kk + g * 8];
                acc[nt] = __builtin_amdgcn_mfma_f32_16x16x32_bf16(af, bfr, acc[nt], 0, 0, 0);
            }
        }
    }

    #pragma unroll
    for (int nt = 0; nt < 4; ++nt) {
        #pragma unroll
        for (int r = 0; r < 4; ++r) {
            int m = m0 + wid * 16 + g * 4 + r;
            out[(size_t)m * HID + n0 + nt * 16 + c] = acc[nt][r];
        }
    }
}

extern "C" void kernel_launch(void* const* d_in, const int* in_sizes, int n_in,
                              void* d_out, int out_size, void* d_ws, size_t ws_size,
                              hipStream_t stream) {
    const float* hs = (const float*)d_in[0];
    const float* Wq = (const float*)d_in[1];
    const float* Wk = (const float*)d_in[2];
    const float* Wv = (const float*)d_in[3];
    const float* Wo = (const float*)d_in[4];
    char* ws = (char*)d_ws;
    bf16* qws  = (bf16*)(ws);                 // [2][8][4096][32]  4,194,304 B
    bf16* kws  = (bf16*)(ws + 4194304);       // [2][4][4096][32]  2,097,152 B
    bf16* vtws = (bf16*)(ws + 6291456);       // [2][4][32][4096]  2,097,152 B
    bf16* att  = (bf16*)(ws + 8388608);       // [2][4096][256]    4,194,304 B

    qkv_proj<<<dim3(8, 128), 256, 0, stream>>>(hs, Wq, Wk, Wv, qws, kws, vtws);
    attn_fwd<<<512, 256, 0, stream>>>(qws, kws, vtws, att);
    out_proj<<<dim3(4, 128), 256, 0, stream>>>(att, Wo, (float*)d_out);
}